// Round 9
// baseline (457.615 us; speedup 1.0000x reference)
//
#include <hip/hip_runtime.h>
#include <hip/hip_bf16.h>
#include <hip/hip_cooperative_groups.h>

namespace cg = cooperative_groups;

// GCN: 2x GCNConv(+self-loops, sym-norm) + ReLU, then Linear(64->1).
// N=100000 nodes, E=1600000 edges, IN=128, HID=64, OUT=1.
//
//  - R8 insight: agg FETCH (85MB) == compulsory floor for 8 non-coherent
//    XCD L2s (12.8MB Tsb x ~8 XCD touch); ~1.5TB/s miss path => ~56us is
//    the floor for this algorithm shape. Agg left as-is.
//  - R8 fix: 8 serialized dispatches carried large launch/drain overhead.
//    CSR build (hist -> scan -> scatter -> bucket-build) fused into ONE
//    cooperative kernel with grid.sync() between phases; scan is now
//    row-parallel multi-block (fixes scan_mat's uncoalesced serial walk).
//  - Ts stored bf16 (packed bf16x2): 128B/edge gather, fp32 accumulate.
//  - norm factored into GEMM epilogue: out[d]=dq_d*(Ts[d]+sum Ts[s]).

#define IN_DIM 128
#define HID 64
#define NBLK 256      // cooperative grid blocks (= level-1 chunks)
#define NTHR 512
#define MAXNC 128     // max coarse buckets (N <= 131072)

typedef unsigned int uint;

__device__ inline uint pack_bf16x2(float a, float b) {
    uint ua = __builtin_bit_cast(uint, a);
    uint ub = __builtin_bit_cast(uint, b);
    ua += 0x7fffu + ((ua >> 16) & 1u);   // RNE
    ub += 0x7fffu + ((ub >> 16) & 1u);
    return (ua >> 16) | (ub & 0xffff0000u);
}
__device__ inline float bf_lo(uint g) { return __builtin_bit_cast(float, g << 16); }
__device__ inline float bf_hi(uint g) { return __builtin_bit_cast(float, g & 0xffff0000u); }

// ---------------- fused CSR build (cooperative) ----------------
// phases: 1) per-chunk coarse histogram (bucket = dst>>10)
//         2) exclusive scan of ghist[bucket][chunk] (row-parallel)
//         3) per-chunk scatter of (src,dst) into bucket segments
//         4) per-bucket exact CSR: LDS hist -> scan -> col scatter
__global__ __launch_bounds__(NTHR) void csr_coop(const int* __restrict__ src,
                                                 const int* __restrict__ dst,
                                                 int* __restrict__ ghist,
                                                 int* __restrict__ rowsum,
                                                 int* __restrict__ rowbase,
                                                 int2* __restrict__ pairs,
                                                 int* __restrict__ row_off,
                                                 float* __restrict__ disqrt,
                                                 int* __restrict__ col,
                                                 int E, int NC, int N) {
    cg::grid_group grid = cg::this_grid();
    __shared__ int hbuf[1024], curb[1024];
    __shared__ int ws16[16], wsoff16[16];
    const int t = threadIdx.x, blk = blockIdx.x;
    const int chunk = (E + NBLK - 1) / NBLK;
    const int s = blk * chunk, e = min(E, s + chunk);

    // ---- phase 1: coarse histogram ----
    if (t < MAXNC) hbuf[t] = 0;
    __syncthreads();
    for (int i = s + t; i < e; i += NTHR) atomicAdd(&hbuf[dst[i] >> 10], 1);
    __syncthreads();
    if (t < NC) ghist[(size_t)t * NBLK + blk] = hbuf[t];
    grid.sync();

    // ---- phase 2a: scan each bucket-row of 256 chunk counts ----
    {
        int v = 0;
        if (blk < NC && t < NBLK) v = ghist[(size_t)blk * NBLK + t];
        int incl = v;
#pragma unroll
        for (int o = 1; o < 64; o <<= 1) {
            int u = __shfl_up(incl, o, 64);
            if ((t & 63) >= o) incl += u;
        }
        if (t < NBLK && (t & 63) == 63) ws16[t >> 6] = incl;
        __syncthreads();
        if (t == 0) {
            int run = 0;
#pragma unroll
            for (int i = 0; i < 4; ++i) { wsoff16[i] = run; run += ws16[i]; }
        }
        __syncthreads();
        if (blk < NC && t < NBLK) {
            int excl = wsoff16[t >> 6] + incl - v;
            ghist[(size_t)blk * NBLK + t] = excl;
            if (t == NBLK - 1) rowsum[blk] = excl + v;
        }
    }
    grid.sync();

    // ---- phase 2b: block 0 scans the NC row sums ----
    if (blk == 0) {
        int v = (t < NC) ? rowsum[t] : 0;
        int incl = v;
#pragma unroll
        for (int o = 1; o < 64; o <<= 1) {
            int u = __shfl_up(incl, o, 64);
            if ((t & 63) >= o) incl += u;
        }
        if ((t & 63) == 63) ws16[t >> 6] = incl;
        __syncthreads();
        if (t == 0) {
            int run = 0;
#pragma unroll
            for (int i = 0; i < 8; ++i) { wsoff16[i] = run; run += ws16[i]; }
            row_off[N] = E;
        }
        __syncthreads();
        if (t < NC) rowbase[t] = wsoff16[t >> 6] + incl - v;
    }
    grid.sync();

    // ---- phase 2c: add row bases ----
    if (blk < NC && t < NBLK) ghist[(size_t)blk * NBLK + t] += rowbase[blk];
    grid.sync();

    // ---- phase 3: scatter (src,dst) into bucket segments ----
    if (t < NC) hbuf[t] = ghist[(size_t)t * NBLK + blk];
    __syncthreads();
    for (int i = s + t; i < e; i += NTHR) {
        int d = dst[i];
        int p = atomicAdd(&hbuf[d >> 10], 1);   // LDS cursor, global pos
        pairs[p] = make_int2(src[i], d);
    }
    grid.sync();

    // ---- phase 4: per-bucket exact CSR build ----
    for (int b = blk; b < NC; b += NBLK) {
        int base = ghist[(size_t)b * NBLK];
        int next = (b + 1 < NC) ? ghist[(size_t)(b + 1) * NBLK] : E;
        hbuf[t] = 0; hbuf[t + 512] = 0;
        __syncthreads();
        for (int i = base + t; i < next; i += NTHR)
            atomicAdd(&hbuf[pairs[i].y & 1023], 1);
        __syncthreads();
        int d0 = hbuf[2 * t], d1 = hbuf[2 * t + 1];
        int ps = d0 + d1;
        int incl = ps;
#pragma unroll
        for (int o = 1; o < 64; o <<= 1) {
            int u = __shfl_up(incl, o, 64);
            if ((t & 63) >= o) incl += u;
        }
        if ((t & 63) == 63) ws16[t >> 6] = incl;
        __syncthreads();
        if (t == 0) {
            int run = 0;
#pragma unroll
            for (int i = 0; i < 8; ++i) { wsoff16[i] = run; run += ws16[i]; }
        }
        __syncthreads();
        int excl = wsoff16[t >> 6] + incl - ps;
        curb[2 * t]     = base + excl;
        curb[2 * t + 1] = base + excl + d0;
        int node = (b << 10) + 2 * t;
        if (node < N) {
            row_off[node] = base + excl;
            disqrt[node]  = rsqrtf((float)(d0 + 1));
        }
        if (node + 1 < N) {
            row_off[node + 1] = base + excl + d0;
            disqrt[node + 1]  = rsqrtf((float)(d1 + 1));
        }
        __syncthreads();
        for (int i = base + t; i < next; i += NTHR) {
            int2 p = pairs[i];
            int pos = atomicAdd(&curb[p.y & 1023], 1);
            col[pos] = p.x;
        }
        __syncthreads();
    }
}

// ---------------- tiled GEMM (pipelined): Ts_bf16 = (X @ W) * disqrt ----------------
template <int K>
__global__ __launch_bounds__(256) void gemm_tile(const float* __restrict__ X,
                                                 const float* __restrict__ W,
                                                 const float* __restrict__ disqrt,
                                                 uint* __restrict__ Tsb, int n) {
    __shared__ float xs[32][68];   // [k][m]; stride 68 keeps rows 16B-aligned
    __shared__ float ws[32][64];   // [k][c]
    const int tid  = threadIdx.x;
    const int nIdx = tid & 15;     // cols 4*nIdx..+3
    const int mIdx = tid >> 4;     // nodes 4*mIdx..+3
    const int m0   = blockIdx.x * 64;
    const int r0 = tid >> 3, kq = tid & 7, r1 = r0 + 32;
    const int wk = tid >> 4, wc = tid & 15;
    const int row0 = m0 + r0, row1 = m0 + r1;
    const float4 z4 = make_float4(0.f, 0.f, 0.f, 0.f);

    float4 gx0 = (row0 < n) ? *(const float4*)(X + (size_t)row0 * K + 4 * kq) : z4;
    float4 gx1 = (row1 < n) ? *(const float4*)(X + (size_t)row1 * K + 4 * kq) : z4;
    float4 gw0 = *(const float4*)(W + (size_t)wk * 64 + 4 * wc);
    float4 gw1 = *(const float4*)(W + (size_t)(wk + 16) * 64 + 4 * wc);

    float acc[4][4] = {};
    for (int kc = 0;;) {
        xs[4 * kq + 0][r0] = gx0.x; xs[4 * kq + 1][r0] = gx0.y;
        xs[4 * kq + 2][r0] = gx0.z; xs[4 * kq + 3][r0] = gx0.w;
        xs[4 * kq + 0][r1] = gx1.x; xs[4 * kq + 1][r1] = gx1.y;
        xs[4 * kq + 2][r1] = gx1.z; xs[4 * kq + 3][r1] = gx1.w;
        *(float4*)&ws[wk][4 * wc]      = gw0;
        *(float4*)&ws[wk + 16][4 * wc] = gw1;
        __syncthreads();
        kc += 32;
        const bool more = kc < K;
        if (more) {
            gx0 = (row0 < n) ? *(const float4*)(X + (size_t)row0 * K + kc + 4 * kq) : z4;
            gx1 = (row1 < n) ? *(const float4*)(X + (size_t)row1 * K + kc + 4 * kq) : z4;
            gw0 = *(const float4*)(W + (size_t)(kc + wk) * 64 + 4 * wc);
            gw1 = *(const float4*)(W + (size_t)(kc + wk + 16) * 64 + 4 * wc);
        }
#pragma unroll 8
        for (int k = 0; k < 32; ++k) {
            float4 a = *(const float4*)&xs[k][4 * mIdx];
            float4 b = *(const float4*)&ws[k][4 * nIdx];
            const float* ap = (const float*)&a;
            const float* bp = (const float*)&b;
#pragma unroll
            for (int mi = 0; mi < 4; ++mi)
#pragma unroll
                for (int ni = 0; ni < 4; ++ni)
                    acc[mi][ni] += ap[mi] * bp[ni];
        }
        if (!more) break;
        __syncthreads();
    }
#pragma unroll
    for (int mi = 0; mi < 4; ++mi) {
        int row = m0 + 4 * mIdx + mi;
        if (row < n) {
            float s = disqrt[row];
            uint2 pk;
            pk.x = pack_bf16x2(acc[mi][0] * s, acc[mi][1] * s);
            pk.y = pack_bf16x2(acc[mi][2] * s, acc[mi][3] * s);
            *(uint2*)(Tsb + (size_t)row * 32 + 2 * nIdx) = pk;
        }
    }
}

// ---------------- aggregation: wave per node, indices preloaded + shfl ----------------
template <bool FUSE_FC>
__global__ __launch_bounds__(256) void agg_kernel(const uint* __restrict__ Tsb,
                                                  const int* __restrict__ row_off,
                                                  const int* __restrict__ col,
                                                  const float* __restrict__ disqrt,
                                                  const float* __restrict__ bias,
                                                  const float* __restrict__ wfc,
                                                  const float* __restrict__ bfc,
                                                  float* __restrict__ out, int n) {
    int node = blockIdx.x * 4 + (threadIdx.x >> 6);
    if (node >= n) return;
    int lane = threadIdx.x & 63;
    int h = lane >> 5;      // half-wave id: which edge of a pair
    int p = lane & 31;      // feature pair index (features 2p, 2p+1)
    float2 acc = make_float2(0.f, 0.f);
    {   // self-loop (half 0 only)
        uint g = Tsb[(size_t)node * 32 + p];
        if (h == 0) { acc.x = bf_lo(g); acc.y = bf_hi(g); }
    }
    int beg = __builtin_amdgcn_readfirstlane(row_off[node]);
    int end = __builtin_amdgcn_readfirstlane(row_off[node + 1]);
    for (int batch = beg; batch < end; batch += 64) {
        int bn = min(64, end - batch);
        int cv = 0;
        if (batch + lane < end) cv = col[batch + lane];  // ONE coalesced load
        int j = 0;
        for (; j + 16 <= bn; j += 16) {
            int s0 = __shfl(cv, j + 0 + h, 64);
            int s1 = __shfl(cv, j + 2 + h, 64);
            int s2 = __shfl(cv, j + 4 + h, 64);
            int s3 = __shfl(cv, j + 6 + h, 64);
            int s4 = __shfl(cv, j + 8 + h, 64);
            int s5 = __shfl(cv, j + 10 + h, 64);
            int s6 = __shfl(cv, j + 12 + h, 64);
            int s7 = __shfl(cv, j + 14 + h, 64);
            uint g0 = Tsb[(size_t)s0 * 32 + p];
            uint g1 = Tsb[(size_t)s1 * 32 + p];
            uint g2 = Tsb[(size_t)s2 * 32 + p];
            uint g3 = Tsb[(size_t)s3 * 32 + p];
            uint g4 = Tsb[(size_t)s4 * 32 + p];
            uint g5 = Tsb[(size_t)s5 * 32 + p];
            uint g6 = Tsb[(size_t)s6 * 32 + p];
            uint g7 = Tsb[(size_t)s7 * 32 + p];
            acc.x += bf_lo(g0); acc.y += bf_hi(g0);
            acc.x += bf_lo(g1); acc.y += bf_hi(g1);
            acc.x += bf_lo(g2); acc.y += bf_hi(g2);
            acc.x += bf_lo(g3); acc.y += bf_hi(g3);
            acc.x += bf_lo(g4); acc.y += bf_hi(g4);
            acc.x += bf_lo(g5); acc.y += bf_hi(g5);
            acc.x += bf_lo(g6); acc.y += bf_hi(g6);
            acc.x += bf_lo(g7); acc.y += bf_hi(g7);
        }
        for (; j + 2 <= bn; j += 2) {
            int s = __shfl(cv, j + h, 64);
            uint g = Tsb[(size_t)s * 32 + p];
            acc.x += bf_lo(g); acc.y += bf_hi(g);
        }
        if (j < bn) {
            int s = __shfl(cv, j, 64);
            uint g = Tsb[(size_t)s * 32 + p];
            if (h == 0) { acc.x += bf_lo(g); acc.y += bf_hi(g); }
        }
    }
    acc.x += __shfl_xor(acc.x, 32, 64);
    acc.y += __shfl_xor(acc.y, 32, 64);
    float dq = disqrt[node];
    float2 bv = *(const float2*)(bias + 2 * p);
    float rx = fmaxf(acc.x * dq + bv.x, 0.f);
    float ry = fmaxf(acc.y * dq + bv.y, 0.f);
    if (!FUSE_FC) {
        if (h == 0)
            *(float2*)(out + (size_t)node * HID + 2 * p) = make_float2(rx, ry);
    } else {
        float2 wv = *(const float2*)(wfc + 2 * p);
        float v = rx * wv.x + ry * wv.y;
        v += __shfl_down(v, 16, 64);
        v += __shfl_down(v, 8, 64);
        v += __shfl_down(v, 4, 64);
        v += __shfl_down(v, 2, 64);
        v += __shfl_down(v, 1, 64);
        if (lane == 0) out[node] = v + bfc[0];
    }
}

extern "C" void kernel_launch(void* const* d_in, const int* in_sizes, int n_in,
                              void* d_out, int out_size, void* d_ws, size_t ws_size,
                              hipStream_t stream) {
    const float* x   = (const float*)d_in[0];
    const int*   ei  = (const int*)d_in[1];
    const float* W1  = (const float*)d_in[2];
    const float* b1  = (const float*)d_in[3];
    const float* W2  = (const float*)d_in[4];
    const float* b2  = (const float*)d_in[5];
    const float* Wfc = (const float*)d_in[6];
    const float* bfc = (const float*)d_in[7];
    float* out = (float*)d_out;

    const int N = in_sizes[0] / IN_DIM;
    const int E = in_sizes[1] / 2;
    const int* src = ei;
    const int* dst = ei + E;
    const int NC = (N + 1023) >> 10;   // coarse buckets (1024 nodes each)

    // ---- workspace carve-up (256B aligned) ----
    char* w = (char*)d_ws;
    auto alloc = [&](size_t bytes) {
        void* p = (void*)w;
        w += (bytes + 255) & ~(size_t)255;
        return p;
    };
    int*   row_off = (int*)alloc((size_t)(N + 1) * 4);
    float* disqrt  = (float*)alloc((size_t)N * 4);
    int*   ghist   = (int*)alloc((size_t)NC * NBLK * 4);
    int*   rowsum  = (int*)alloc((size_t)MAXNC * 4);
    int*   rowbase = (int*)alloc((size_t)MAXNC * 4);
    int*   col     = (int*)alloc((size_t)E * 4);
    size_t scrA = (size_t)E * 8, scrB = (size_t)N * HID * 2;
    void*  scr  = alloc(scrA > scrB ? scrA : scrB);
    float* h1   = (float*)alloc((size_t)N * HID * 4);
    int2*  pairs = (int2*)scr;
    uint*  Tsb   = (uint*)scr;

    // ---- build CSR: one cooperative dispatch ----
    {
        int e_ = E, nc_ = NC, n_ = N;
        void* args[] = {(void*)&src, (void*)&dst, (void*)&ghist, (void*)&rowsum,
                        (void*)&rowbase, (void*)&pairs, (void*)&row_off,
                        (void*)&disqrt, (void*)&col, (void*)&e_, (void*)&nc_,
                        (void*)&n_};
        hipLaunchCooperativeKernel((void*)csr_coop, dim3(NBLK), dim3(NTHR),
                                   args, 0, stream);
    }

    // ---- layer 1 ----
    gemm_tile<IN_DIM><<<(N + 63) / 64, 256, 0, stream>>>(x, W1, disqrt, Tsb, N);
    agg_kernel<false><<<(N + 3) / 4, 256, 0, stream>>>(Tsb, row_off, col, disqrt,
                                                       b1, nullptr, nullptr, h1, N);

    // ---- layer 2 + fused fc ----
    gemm_tile<HID><<<(N + 63) / 64, 256, 0, stream>>>(h1, W2, disqrt, Tsb, N);
    agg_kernel<true><<<(N + 3) / 4, 256, 0, stream>>>(Tsb, row_off, col, disqrt,
                                                      b2, Wfc, bfc, out, N);
}

// Round 10
// 301.967 us; speedup vs baseline: 1.5154x; 1.5154x over previous
//
#include <hip/hip_runtime.h>
#include <hip/hip_bf16.h>

// GCN: 2x GCNConv(+self-loops, sym-norm) + ReLU, then Linear(64->1).
// N=100000 nodes, E=1600000 edges, IN=128, HID=64, OUT=1.
//
//  - R9 post-mortem: cooperative CSR fusion regressed 320->457us (6x
//    grid.sync spin barriers; 0.75% VALU). REVERTED to 4-kernel chain.
//  - R10: pairs packed to 4B ((src<<10)|loc) -> halves scatter1 write +
//    build_csr read. Agg: quarter-wave per edge (16 lanes x uint2 = same
//    128B/edge, but 4 edges per VMEM instruction) to test whether agg is
//    VMEM-issue-bound vs line-latency-bound.
//  - Ts stored bf16 (packed bf16x2); fp32 accumulate.
//  - norm factored into GEMM epilogue: out[d]=dq_d*(Ts[d]+sum Ts[s]).

#define IN_DIM 128
#define HID 64
#define B1 256        // level-1 blocks (chunks)
#define MAXNC 128     // max coarse buckets (N <= 131072)

typedef unsigned int uint;

__device__ inline uint pack_bf16x2(float a, float b) {
    uint ua = __builtin_bit_cast(uint, a);
    uint ub = __builtin_bit_cast(uint, b);
    ua += 0x7fffu + ((ua >> 16) & 1u);   // RNE
    ub += 0x7fffu + ((ub >> 16) & 1u);
    return (ua >> 16) | (ub & 0xffff0000u);
}
__device__ inline float bf_lo(uint g) { return __builtin_bit_cast(float, g << 16); }
__device__ inline float bf_hi(uint g) { return __builtin_bit_cast(float, g & 0xffff0000u); }

// ---------------- level-1 histogram: coarse buckets (dst>>10) per chunk ----------------
__global__ __launch_bounds__(512) void hist1(const int* __restrict__ dst,
                                             int* __restrict__ ghist,
                                             int E, int NC, int chunk) {
    __shared__ int h[MAXNC];
    int t = threadIdx.x, blk = blockIdx.x;
    if (t < NC) h[t] = 0;
    __syncthreads();
    int s = blk * chunk, e = min(E, s + chunk);
    for (int i = s + t; i < e; i += 512) atomicAdd(&h[dst[i] >> 10], 1);
    __syncthreads();
    if (t < NC) ghist[(size_t)t * B1 + blk] = h[t];
}

// ---------------- exclusive scan of ghist (NC*B1 elems, in place) ----------------
__global__ __launch_bounds__(1024) void scan_mat(int* __restrict__ a, int M,
                                                 int* __restrict__ row_off, int N) {
    __shared__ int ws[16], wsoff[16], total_s;
    int t = threadIdx.x;
    int seg = (M + 1023) >> 10;
    int s = t * seg, e = min(M, s + seg);
    int sum = 0;
    for (int i = s; i < e; ++i) sum += a[i];
    int incl = sum;
#pragma unroll
    for (int o = 1; o < 64; o <<= 1) {
        int u = __shfl_up(incl, o, 64);
        if ((t & 63) >= o) incl += u;
    }
    if ((t & 63) == 63) ws[t >> 6] = incl;
    __syncthreads();
    if (t == 0) {
        int run = 0;
#pragma unroll
        for (int i = 0; i < 16; ++i) { wsoff[i] = run; run += ws[i]; }
        total_s = run;
    }
    __syncthreads();
    int run = wsoff[t >> 6] + incl - sum;  // exclusive prefix at segment start
    for (int i = s; i < e; ++i) { int tmp = a[i]; a[i] = run; run += tmp; }
    if (t == 0) row_off[N] = total_s;  // == E
}

// ---------------- level-1 scatter: packed 4B pairs, sequential runs ----------------
__global__ __launch_bounds__(512) void scatter1(const int* __restrict__ src,
                                                const int* __restrict__ dst,
                                                const int* __restrict__ goff,
                                                uint* __restrict__ pairs,
                                                int E, int NC, int chunk) {
    __shared__ int cur[MAXNC];
    int t = threadIdx.x, blk = blockIdx.x;
    if (t < NC) cur[t] = goff[(size_t)t * B1 + blk];
    __syncthreads();
    int s = blk * chunk, e = min(E, s + chunk);
    for (int i = s + t; i < e; i += 512) {
        int d = dst[i];
        int p = atomicAdd(&cur[d >> 10], 1);  // LDS cursor holds global pos
        pairs[p] = ((uint)src[i] << 10) | (uint)(d & 1023);
    }
}

// ---------------- level-2: per-bucket CSR build (exact) ----------------
__global__ __launch_bounds__(1024) void build_csr(const uint* __restrict__ pairs,
                                                  const int* __restrict__ goff,
                                                  int* __restrict__ row_off,
                                                  float* __restrict__ disqrt,
                                                  int* __restrict__ col,
                                                  int E, int NC, int N) {
    __shared__ int h[1024], cur[1024];
    __shared__ int ws[16], wsoff[16];
    int b = blockIdx.x, t = threadIdx.x;
    int base = goff[(size_t)b * B1];
    int next = (b + 1 < NC) ? goff[(size_t)(b + 1) * B1] : E;
    h[t] = 0;
    __syncthreads();
    for (int i = base + t; i < next; i += 1024)
        atomicAdd(&h[pairs[i] & 1023u], 1);
    __syncthreads();
    int deg = h[t];
    int incl = deg;
#pragma unroll
    for (int o = 1; o < 64; o <<= 1) {
        int u = __shfl_up(incl, o, 64);
        if ((t & 63) >= o) incl += u;
    }
    if ((t & 63) == 63) ws[t >> 6] = incl;
    __syncthreads();
    if (t == 0) {
        int run = 0;
#pragma unroll
        for (int i = 0; i < 16; ++i) { wsoff[i] = run; run += ws[i]; }
    }
    __syncthreads();
    int excl = wsoff[t >> 6] + incl - deg;
    cur[t] = base + excl;
    int node = (b << 10) + t;
    if (node < N) {
        row_off[node] = base + excl;
        disqrt[node]  = rsqrtf((float)(deg + 1));  // +1 self-loop
    }
    __syncthreads();
    for (int i = base + t; i < next; i += 1024) {
        uint p = pairs[i];
        int pos = atomicAdd(&cur[p & 1023u], 1);  // LDS atomic, global pos
        col[pos] = (int)(p >> 10);                // 65KB window, single XCD
    }
}

// ---------------- tiled GEMM (pipelined): Ts_bf16 = (X @ W) * disqrt ----------------
template <int K>
__global__ __launch_bounds__(256) void gemm_tile(const float* __restrict__ X,
                                                 const float* __restrict__ W,
                                                 const float* __restrict__ disqrt,
                                                 uint* __restrict__ Tsb, int n) {
    __shared__ float xs[32][68];   // [k][m]; stride 68 keeps rows 16B-aligned
    __shared__ float ws[32][64];   // [k][c]
    const int tid  = threadIdx.x;
    const int nIdx = tid & 15;     // cols 4*nIdx..+3
    const int mIdx = tid >> 4;     // nodes 4*mIdx..+3
    const int m0   = blockIdx.x * 64;
    const int r0 = tid >> 3, kq = tid & 7, r1 = r0 + 32;
    const int wk = tid >> 4, wc = tid & 15;
    const int row0 = m0 + r0, row1 = m0 + r1;
    const float4 z4 = make_float4(0.f, 0.f, 0.f, 0.f);

    float4 gx0 = (row0 < n) ? *(const float4*)(X + (size_t)row0 * K + 4 * kq) : z4;
    float4 gx1 = (row1 < n) ? *(const float4*)(X + (size_t)row1 * K + 4 * kq) : z4;
    float4 gw0 = *(const float4*)(W + (size_t)wk * 64 + 4 * wc);
    float4 gw1 = *(const float4*)(W + (size_t)(wk + 16) * 64 + 4 * wc);

    float acc[4][4] = {};
    for (int kc = 0;;) {
        xs[4 * kq + 0][r0] = gx0.x; xs[4 * kq + 1][r0] = gx0.y;
        xs[4 * kq + 2][r0] = gx0.z; xs[4 * kq + 3][r0] = gx0.w;
        xs[4 * kq + 0][r1] = gx1.x; xs[4 * kq + 1][r1] = gx1.y;
        xs[4 * kq + 2][r1] = gx1.z; xs[4 * kq + 3][r1] = gx1.w;
        *(float4*)&ws[wk][4 * wc]      = gw0;
        *(float4*)&ws[wk + 16][4 * wc] = gw1;
        __syncthreads();
        kc += 32;
        const bool more = kc < K;
        if (more) {  // prefetch next chunk; latency overlaps compute below
            gx0 = (row0 < n) ? *(const float4*)(X + (size_t)row0 * K + kc + 4 * kq) : z4;
            gx1 = (row1 < n) ? *(const float4*)(X + (size_t)row1 * K + kc + 4 * kq) : z4;
            gw0 = *(const float4*)(W + (size_t)(kc + wk) * 64 + 4 * wc);
            gw1 = *(const float4*)(W + (size_t)(kc + wk + 16) * 64 + 4 * wc);
        }
#pragma unroll 8
        for (int k = 0; k < 32; ++k) {
            float4 a = *(const float4*)&xs[k][4 * mIdx];
            float4 b = *(const float4*)&ws[k][4 * nIdx];
            const float* ap = (const float*)&a;
            const float* bp = (const float*)&b;
#pragma unroll
            for (int mi = 0; mi < 4; ++mi)
#pragma unroll
                for (int ni = 0; ni < 4; ++ni)
                    acc[mi][ni] += ap[mi] * bp[ni];
        }
        if (!more) break;
        __syncthreads();
    }
#pragma unroll
    for (int mi = 0; mi < 4; ++mi) {
        int row = m0 + 4 * mIdx + mi;
        if (row < n) {
            float s = disqrt[row];
            uint2 pk;
            pk.x = pack_bf16x2(acc[mi][0] * s, acc[mi][1] * s);
            pk.y = pack_bf16x2(acc[mi][2] * s, acc[mi][3] * s);
            *(uint2*)(Tsb + (size_t)row * 32 + 2 * nIdx) = pk;
        }
    }
}

// ---------------- aggregation: wave per node, QUARTER-wave per edge ----------------
// out[d] = relu(disqrt[d] * (Ts[d] + sum_e Ts[col[e]]) + bias)
// Tsb: packed bf16x2, 32 uints/row (128B). 16 lanes x uint2 per edge ->
// 4 edges per VMEM instruction. Lane p = lane&15 holds features 4p..4p+3.
template <bool FUSE_FC>
__global__ __launch_bounds__(256) void agg_kernel(const uint* __restrict__ Tsb,
                                                  const int* __restrict__ row_off,
                                                  const int* __restrict__ col,
                                                  const float* __restrict__ disqrt,
                                                  const float* __restrict__ bias,
                                                  const float* __restrict__ wfc,
                                                  const float* __restrict__ bfc,
                                                  float* __restrict__ out, int n) {
    int node = blockIdx.x * 4 + (threadIdx.x >> 6);
    if (node >= n) return;
    int lane = threadIdx.x & 63;
    int q = lane >> 4;      // quarter id: which edge of a group of 4
    int p = lane & 15;      // uint2 index (features 4p..4p+3)
    float4 acc = make_float4(0.f, 0.f, 0.f, 0.f);
    if (q == 0) {   // self-loop, quarter 0 only
        uint2 g = *(const uint2*)(Tsb + (size_t)node * 32 + 2 * p);
        acc.x = bf_lo(g.x); acc.y = bf_hi(g.x);
        acc.z = bf_lo(g.y); acc.w = bf_hi(g.y);
    }
    int beg = __builtin_amdgcn_readfirstlane(row_off[node]);
    int end = __builtin_amdgcn_readfirstlane(row_off[node + 1]);
    for (int batch = beg; batch < end; batch += 64) {
        int bn = min(64, end - batch);
        int cv = 0;
        if (batch + lane < end) cv = col[batch + lane];  // ONE coalesced load
        int j = 0;
        for (; j + 16 <= bn; j += 16) {   // 16 edges: 4 gathers in flight/quarter
            int s0 = __shfl(cv, j + q, 64);
            int s1 = __shfl(cv, j + 4 + q, 64);
            int s2 = __shfl(cv, j + 8 + q, 64);
            int s3 = __shfl(cv, j + 12 + q, 64);
            uint2 g0 = *(const uint2*)(Tsb + (size_t)s0 * 32 + 2 * p);
            uint2 g1 = *(const uint2*)(Tsb + (size_t)s1 * 32 + 2 * p);
            uint2 g2 = *(const uint2*)(Tsb + (size_t)s2 * 32 + 2 * p);
            uint2 g3 = *(const uint2*)(Tsb + (size_t)s3 * 32 + 2 * p);
            acc.x += bf_lo(g0.x); acc.y += bf_hi(g0.x);
            acc.z += bf_lo(g0.y); acc.w += bf_hi(g0.y);
            acc.x += bf_lo(g1.x); acc.y += bf_hi(g1.x);
            acc.z += bf_lo(g1.y); acc.w += bf_hi(g1.y);
            acc.x += bf_lo(g2.x); acc.y += bf_hi(g2.x);
            acc.z += bf_lo(g2.y); acc.w += bf_hi(g2.y);
            acc.x += bf_lo(g3.x); acc.y += bf_hi(g3.x);
            acc.z += bf_lo(g3.y); acc.w += bf_hi(g3.y);
        }
        for (; j < bn; j += 4) {          // tail: 4 edges per step, predicated
            int idx = j + q;
            int s = __shfl(cv, idx & 63, 64);  // cv=0 for OOB lanes -> safe addr
            uint2 g = *(const uint2*)(Tsb + (size_t)s * 32 + 2 * p);
            if (idx < bn) {
                acc.x += bf_lo(g.x); acc.y += bf_hi(g.x);
                acc.z += bf_lo(g.y); acc.w += bf_hi(g.y);
            }
        }
    }
    // combine quarters
    acc.x += __shfl_xor(acc.x, 16, 64);
    acc.y += __shfl_xor(acc.y, 16, 64);
    acc.z += __shfl_xor(acc.z, 16, 64);
    acc.w += __shfl_xor(acc.w, 16, 64);
    acc.x += __shfl_xor(acc.x, 32, 64);
    acc.y += __shfl_xor(acc.y, 32, 64);
    acc.z += __shfl_xor(acc.z, 32, 64);
    acc.w += __shfl_xor(acc.w, 32, 64);
    float dq = disqrt[node];
    float4 bv = *(const float4*)(bias + 4 * p);
    float r0 = fmaxf(acc.x * dq + bv.x, 0.f);
    float r1 = fmaxf(acc.y * dq + bv.y, 0.f);
    float r2 = fmaxf(acc.z * dq + bv.z, 0.f);
    float r3 = fmaxf(acc.w * dq + bv.w, 0.f);
    if (!FUSE_FC) {
        if (q == 0)
            *(float4*)(out + (size_t)node * HID + 4 * p) =
                make_float4(r0, r1, r2, r3);
    } else {
        float4 wv = *(const float4*)(wfc + 4 * p);
        float v = r0 * wv.x + r1 * wv.y + r2 * wv.z + r3 * wv.w;
        v += __shfl_down(v, 8, 64);
        v += __shfl_down(v, 4, 64);
        v += __shfl_down(v, 2, 64);
        v += __shfl_down(v, 1, 64);
        if (lane == 0) out[node] = v + bfc[0];
    }
}

extern "C" void kernel_launch(void* const* d_in, const int* in_sizes, int n_in,
                              void* d_out, int out_size, void* d_ws, size_t ws_size,
                              hipStream_t stream) {
    const float* x   = (const float*)d_in[0];
    const int*   ei  = (const int*)d_in[1];
    const float* W1  = (const float*)d_in[2];
    const float* b1  = (const float*)d_in[3];
    const float* W2  = (const float*)d_in[4];
    const float* b2  = (const float*)d_in[5];
    const float* Wfc = (const float*)d_in[6];
    const float* bfc = (const float*)d_in[7];
    float* out = (float*)d_out;

    const int N = in_sizes[0] / IN_DIM;
    const int E = in_sizes[1] / 2;
    const int* src = ei;
    const int* dst = ei + E;
    const int NC    = (N + 1023) >> 10;      // coarse buckets (1024 nodes each)
    const int chunk = (E + B1 - 1) / B1;     // edges per level-1 block

    // ---- workspace carve-up (256B aligned) ----
    char* w = (char*)d_ws;
    auto alloc = [&](size_t bytes) {
        void* p = (void*)w;
        w += (bytes + 255) & ~(size_t)255;
        return p;
    };
    int*   row_off = (int*)alloc((size_t)(N + 1) * 4);
    float* disqrt  = (float*)alloc((size_t)N * 4);
    int*   goff    = (int*)alloc((size_t)NC * B1 * 4);
    int*   col     = (int*)alloc((size_t)E * 4);
    // scratch region reused: packed pairs (E*4) first, then Ts bf16 (N*128B)
    size_t scrA = (size_t)E * 4, scrB = (size_t)N * HID * 2;
    void*  scr  = alloc(scrA > scrB ? scrA : scrB);
    float* h1   = (float*)alloc((size_t)N * HID * 4);
    uint*  pairs = (uint*)scr;
    uint*  Tsb   = (uint*)scr;

    // ---- build CSR (exact two-level counting sort, packed pairs) ----
    hist1<<<B1, 512, 0, stream>>>(dst, goff, E, NC, chunk);
    scan_mat<<<1, 1024, 0, stream>>>(goff, NC * B1, row_off, N);
    scatter1<<<B1, 512, 0, stream>>>(src, dst, goff, pairs, E, NC, chunk);
    build_csr<<<NC, 1024, 0, stream>>>(pairs, goff, row_off, disqrt, col, E, NC, N);

    // ---- layer 1 ----
    gemm_tile<IN_DIM><<<(N + 63) / 64, 256, 0, stream>>>(x, W1, disqrt, Tsb, N);
    agg_kernel<false><<<(N + 3) / 4, 256, 0, stream>>>(Tsb, row_off, col, disqrt,
                                                       b1, nullptr, nullptr, h1, N);

    // ---- layer 2 + fused fc ----
    gemm_tile<HID><<<(N + 63) / 64, 256, 0, stream>>>(h1, W2, disqrt, Tsb, N);
    agg_kernel<true><<<(N + 3) / 4, 256, 0, stream>>>(Tsb, row_off, col, disqrt,
                                                      b2, Wfc, bfc, out, N);
}

// Round 11
// 300.132 us; speedup vs baseline: 1.5247x; 1.0061x over previous
//
#include <hip/hip_runtime.h>
#include <hip/hip_bf16.h>

// GCN: 2x GCNConv(+self-loops, sym-norm) + ReLU, then Linear(64->1).
// N=100000 nodes, E=1600000 edges, IN=128, HID=64, OUT=1.
//
//  - R10 post-mortem: quarter-wave agg 56->48us => agg is VMEM-issue
//    bound (not pure line latency). R11: EIGHTH-wave (8 lanes x uint4,
//    8 edges/VMEM instr) halves issue count again. h1 now bf16 packed
//    (agg1 packs, gemm_tile_b consumes) -> 25.6MB less traffic.
//  - Exact two-level counting-sort CSR (packed 4B pairs).
//  - Ts stored bf16 (packed bf16x2); fp32 accumulate everywhere.
//  - norm factored into GEMM epilogue: out[d]=dq_d*(Ts[d]+sum Ts[s]).

#define IN_DIM 128
#define HID 64
#define B1 256        // level-1 blocks (chunks)
#define MAXNC 128     // max coarse buckets (N <= 131072)

typedef unsigned int uint;

__device__ inline uint pack_bf16x2(float a, float b) {
    uint ua = __builtin_bit_cast(uint, a);
    uint ub = __builtin_bit_cast(uint, b);
    ua += 0x7fffu + ((ua >> 16) & 1u);   // RNE
    ub += 0x7fffu + ((ub >> 16) & 1u);
    return (ua >> 16) | (ub & 0xffff0000u);
}
__device__ inline float bf_lo(uint g) { return __builtin_bit_cast(float, g << 16); }
__device__ inline float bf_hi(uint g) { return __builtin_bit_cast(float, g & 0xffff0000u); }

// ---------------- level-1 histogram: coarse buckets (dst>>10) per chunk ----------------
__global__ __launch_bounds__(512) void hist1(const int* __restrict__ dst,
                                             int* __restrict__ ghist,
                                             int E, int NC, int chunk) {
    __shared__ int h[MAXNC];
    int t = threadIdx.x, blk = blockIdx.x;
    if (t < NC) h[t] = 0;
    __syncthreads();
    int s = blk * chunk, e = min(E, s + chunk);
    for (int i = s + t; i < e; i += 512) atomicAdd(&h[dst[i] >> 10], 1);
    __syncthreads();
    if (t < NC) ghist[(size_t)t * B1 + blk] = h[t];
}

// ---------------- exclusive scan of ghist (NC*B1 elems, in place) ----------------
__global__ __launch_bounds__(1024) void scan_mat(int* __restrict__ a, int M,
                                                 int* __restrict__ row_off, int N) {
    __shared__ int ws[16], wsoff[16], total_s;
    int t = threadIdx.x;
    int seg = (M + 1023) >> 10;
    int s = t * seg, e = min(M, s + seg);
    int sum = 0;
    for (int i = s; i < e; ++i) sum += a[i];
    int incl = sum;
#pragma unroll
    for (int o = 1; o < 64; o <<= 1) {
        int u = __shfl_up(incl, o, 64);
        if ((t & 63) >= o) incl += u;
    }
    if ((t & 63) == 63) ws[t >> 6] = incl;
    __syncthreads();
    if (t == 0) {
        int run = 0;
#pragma unroll
        for (int i = 0; i < 16; ++i) { wsoff[i] = run; run += ws[i]; }
        total_s = run;
    }
    __syncthreads();
    int run = wsoff[t >> 6] + incl - sum;  // exclusive prefix at segment start
    for (int i = s; i < e; ++i) { int tmp = a[i]; a[i] = run; run += tmp; }
    if (t == 0) row_off[N] = total_s;  // == E
}

// ---------------- level-1 scatter: packed 4B pairs, sequential runs ----------------
__global__ __launch_bounds__(512) void scatter1(const int* __restrict__ src,
                                                const int* __restrict__ dst,
                                                const int* __restrict__ goff,
                                                uint* __restrict__ pairs,
                                                int E, int NC, int chunk) {
    __shared__ int cur[MAXNC];
    int t = threadIdx.x, blk = blockIdx.x;
    if (t < NC) cur[t] = goff[(size_t)t * B1 + blk];
    __syncthreads();
    int s = blk * chunk, e = min(E, s + chunk);
    for (int i = s + t; i < e; i += 512) {
        int d = dst[i];
        int p = atomicAdd(&cur[d >> 10], 1);  // LDS cursor holds global pos
        pairs[p] = ((uint)src[i] << 10) | (uint)(d & 1023);
    }
}

// ---------------- level-2: per-bucket CSR build (exact) ----------------
__global__ __launch_bounds__(1024) void build_csr(const uint* __restrict__ pairs,
                                                  const int* __restrict__ goff,
                                                  int* __restrict__ row_off,
                                                  float* __restrict__ disqrt,
                                                  int* __restrict__ col,
                                                  int E, int NC, int N) {
    __shared__ int h[1024], cur[1024];
    __shared__ int ws[16], wsoff[16];
    int b = blockIdx.x, t = threadIdx.x;
    int base = goff[(size_t)b * B1];
    int next = (b + 1 < NC) ? goff[(size_t)(b + 1) * B1] : E;
    h[t] = 0;
    __syncthreads();
    for (int i = base + t; i < next; i += 1024)
        atomicAdd(&h[pairs[i] & 1023u], 1);
    __syncthreads();
    int deg = h[t];
    int incl = deg;
#pragma unroll
    for (int o = 1; o < 64; o <<= 1) {
        int u = __shfl_up(incl, o, 64);
        if ((t & 63) >= o) incl += u;
    }
    if ((t & 63) == 63) ws[t >> 6] = incl;
    __syncthreads();
    if (t == 0) {
        int run = 0;
#pragma unroll
        for (int i = 0; i < 16; ++i) { wsoff[i] = run; run += ws[i]; }
    }
    __syncthreads();
    int excl = wsoff[t >> 6] + incl - deg;
    cur[t] = base + excl;
    int node = (b << 10) + t;
    if (node < N) {
        row_off[node] = base + excl;
        disqrt[node]  = rsqrtf((float)(deg + 1));  // +1 self-loop
    }
    __syncthreads();
    for (int i = base + t; i < next; i += 1024) {
        uint p = pairs[i];
        int pos = atomicAdd(&cur[p & 1023u], 1);  // LDS atomic, global pos
        col[pos] = (int)(p >> 10);                // 65KB window, single XCD
    }
}

// ---------------- tiled GEMM (fp32 X): Ts_bf16 = (X @ W) * disqrt ----------------
template <int K>
__global__ __launch_bounds__(256) void gemm_tile(const float* __restrict__ X,
                                                 const float* __restrict__ W,
                                                 const float* __restrict__ disqrt,
                                                 uint* __restrict__ Tsb, int n) {
    __shared__ float xs[32][68];   // [k][m]; stride 68 keeps rows 16B-aligned
    __shared__ float ws[32][64];   // [k][c]
    const int tid  = threadIdx.x;
    const int nIdx = tid & 15;     // cols 4*nIdx..+3
    const int mIdx = tid >> 4;     // nodes 4*mIdx..+3
    const int m0   = blockIdx.x * 64;
    const int r0 = tid >> 3, kq = tid & 7, r1 = r0 + 32;
    const int wk = tid >> 4, wc = tid & 15;
    const int row0 = m0 + r0, row1 = m0 + r1;
    const float4 z4 = make_float4(0.f, 0.f, 0.f, 0.f);

    float4 gx0 = (row0 < n) ? *(const float4*)(X + (size_t)row0 * K + 4 * kq) : z4;
    float4 gx1 = (row1 < n) ? *(const float4*)(X + (size_t)row1 * K + 4 * kq) : z4;
    float4 gw0 = *(const float4*)(W + (size_t)wk * 64 + 4 * wc);
    float4 gw1 = *(const float4*)(W + (size_t)(wk + 16) * 64 + 4 * wc);

    float acc[4][4] = {};
    for (int kc = 0;;) {
        xs[4 * kq + 0][r0] = gx0.x; xs[4 * kq + 1][r0] = gx0.y;
        xs[4 * kq + 2][r0] = gx0.z; xs[4 * kq + 3][r0] = gx0.w;
        xs[4 * kq + 0][r1] = gx1.x; xs[4 * kq + 1][r1] = gx1.y;
        xs[4 * kq + 2][r1] = gx1.z; xs[4 * kq + 3][r1] = gx1.w;
        *(float4*)&ws[wk][4 * wc]      = gw0;
        *(float4*)&ws[wk + 16][4 * wc] = gw1;
        __syncthreads();
        kc += 32;
        const bool more = kc < K;
        if (more) {  // prefetch next chunk; latency overlaps compute below
            gx0 = (row0 < n) ? *(const float4*)(X + (size_t)row0 * K + kc + 4 * kq) : z4;
            gx1 = (row1 < n) ? *(const float4*)(X + (size_t)row1 * K + kc + 4 * kq) : z4;
            gw0 = *(const float4*)(W + (size_t)(kc + wk) * 64 + 4 * wc);
            gw1 = *(const float4*)(W + (size_t)(kc + wk + 16) * 64 + 4 * wc);
        }
#pragma unroll 8
        for (int k = 0; k < 32; ++k) {
            float4 a = *(const float4*)&xs[k][4 * mIdx];
            float4 b = *(const float4*)&ws[k][4 * nIdx];
            const float* ap = (const float*)&a;
            const float* bp = (const float*)&b;
#pragma unroll
            for (int mi = 0; mi < 4; ++mi)
#pragma unroll
                for (int ni = 0; ni < 4; ++ni)
                    acc[mi][ni] += ap[mi] * bp[ni];
        }
        if (!more) break;
        __syncthreads();
    }
#pragma unroll
    for (int mi = 0; mi < 4; ++mi) {
        int row = m0 + 4 * mIdx + mi;
        if (row < n) {
            float s = disqrt[row];
            uint2 pk;
            pk.x = pack_bf16x2(acc[mi][0] * s, acc[mi][1] * s);
            pk.y = pack_bf16x2(acc[mi][2] * s, acc[mi][3] * s);
            *(uint2*)(Tsb + (size_t)row * 32 + 2 * nIdx) = pk;
        }
    }
}

// ---------------- tiled GEMM (bf16 X, K=64): Ts_bf16 = (Xb @ W) * disqrt ----------------
__global__ __launch_bounds__(256) void gemm_tile_b(const uint* __restrict__ Xb,
                                                   const float* __restrict__ W,
                                                   const float* __restrict__ disqrt,
                                                   uint* __restrict__ Tsb, int n) {
    const int K = 64;
    __shared__ float xs[32][68];
    __shared__ float ws[32][64];
    const int tid  = threadIdx.x;
    const int nIdx = tid & 15;
    const int mIdx = tid >> 4;
    const int m0   = blockIdx.x * 64;
    const int r0 = tid >> 3, kq = tid & 7, r1 = r0 + 32;
    const int wk = tid >> 4, wc = tid & 15;
    const int row0 = m0 + r0, row1 = m0 + r1;
    const uint2 z2 = make_uint2(0u, 0u);

    // X row = 32 uints (64 bf16). Chunk kc covers uints kc/2 .. kc/2+15.
    uint2 gx0 = (row0 < n) ? *(const uint2*)(Xb + (size_t)row0 * 32 + 2 * kq) : z2;
    uint2 gx1 = (row1 < n) ? *(const uint2*)(Xb + (size_t)row1 * 32 + 2 * kq) : z2;
    float4 gw0 = *(const float4*)(W + (size_t)wk * 64 + 4 * wc);
    float4 gw1 = *(const float4*)(W + (size_t)(wk + 16) * 64 + 4 * wc);

    float acc[4][4] = {};
    for (int kc = 0;;) {
        xs[4 * kq + 0][r0] = bf_lo(gx0.x); xs[4 * kq + 1][r0] = bf_hi(gx0.x);
        xs[4 * kq + 2][r0] = bf_lo(gx0.y); xs[4 * kq + 3][r0] = bf_hi(gx0.y);
        xs[4 * kq + 0][r1] = bf_lo(gx1.x); xs[4 * kq + 1][r1] = bf_hi(gx1.x);
        xs[4 * kq + 2][r1] = bf_lo(gx1.y); xs[4 * kq + 3][r1] = bf_hi(gx1.y);
        *(float4*)&ws[wk][4 * wc]      = gw0;
        *(float4*)&ws[wk + 16][4 * wc] = gw1;
        __syncthreads();
        kc += 32;
        const bool more = kc < K;
        if (more) {
            gx0 = (row0 < n) ? *(const uint2*)(Xb + (size_t)row0 * 32 + 16 + 2 * kq) : z2;
            gx1 = (row1 < n) ? *(const uint2*)(Xb + (size_t)row1 * 32 + 16 + 2 * kq) : z2;
            gw0 = *(const float4*)(W + (size_t)(kc + wk) * 64 + 4 * wc);
            gw1 = *(const float4*)(W + (size_t)(kc + wk + 16) * 64 + 4 * wc);
        }
#pragma unroll 8
        for (int k = 0; k < 32; ++k) {
            float4 a = *(const float4*)&xs[k][4 * mIdx];
            float4 b = *(const float4*)&ws[k][4 * nIdx];
            const float* ap = (const float*)&a;
            const float* bp = (const float*)&b;
#pragma unroll
            for (int mi = 0; mi < 4; ++mi)
#pragma unroll
                for (int ni = 0; ni < 4; ++ni)
                    acc[mi][ni] += ap[mi] * bp[ni];
        }
        if (!more) break;
        __syncthreads();
    }
#pragma unroll
    for (int mi = 0; mi < 4; ++mi) {
        int row = m0 + 4 * mIdx + mi;
        if (row < n) {
            float s = disqrt[row];
            uint2 pk;
            pk.x = pack_bf16x2(acc[mi][0] * s, acc[mi][1] * s);
            pk.y = pack_bf16x2(acc[mi][2] * s, acc[mi][3] * s);
            *(uint2*)(Tsb + (size_t)row * 32 + 2 * nIdx) = pk;
        }
    }
}

// ---------------- aggregation: wave per node, EIGHTH-wave per edge ----------------
// out[d] = relu(disqrt[d] * (Ts[d] + sum_e Ts[col[e]]) + bias)
// Tsb: packed bf16x2, 32 uints/row (128B). 8 lanes x uint4 per edge ->
// 8 edges per VMEM instruction. Lane p = lane&7 holds features 8p..8p+7.
template <bool FUSE_FC>
__global__ __launch_bounds__(256) void agg_kernel(const uint* __restrict__ Tsb,
                                                  const int* __restrict__ row_off,
                                                  const int* __restrict__ col,
                                                  const float* __restrict__ disqrt,
                                                  const float* __restrict__ bias,
                                                  const float* __restrict__ wfc,
                                                  const float* __restrict__ bfc,
                                                  uint* __restrict__ outb,
                                                  float* __restrict__ outf, int n) {
    int node = blockIdx.x * 4 + (threadIdx.x >> 6);
    if (node >= n) return;
    int lane = threadIdx.x & 63;
    int o = lane >> 3;      // octant id: edge slot within group of 8
    int p = lane & 7;       // uint4 index (features 8p..8p+7)
    float acc[8] = {};
    if (o == 0) {   // self-loop, octant 0 only
        uint4 g = *(const uint4*)(Tsb + (size_t)node * 32 + 4 * p);
        acc[0] = bf_lo(g.x); acc[1] = bf_hi(g.x);
        acc[2] = bf_lo(g.y); acc[3] = bf_hi(g.y);
        acc[4] = bf_lo(g.z); acc[5] = bf_hi(g.z);
        acc[6] = bf_lo(g.w); acc[7] = bf_hi(g.w);
    }
    int beg = __builtin_amdgcn_readfirstlane(row_off[node]);
    int end = __builtin_amdgcn_readfirstlane(row_off[node + 1]);
    for (int batch = beg; batch < end; batch += 64) {
        int bn = min(64, end - batch);
        int cv = 0;
        if (batch + lane < end) cv = col[batch + lane];  // ONE coalesced load
        int j = 0;
        for (; j + 16 <= bn; j += 16) {   // 16 edges: 2 gathers in flight/octant
            int s0 = __shfl(cv, j + o, 64);
            int s1 = __shfl(cv, j + 8 + o, 64);
            uint4 g0 = *(const uint4*)(Tsb + (size_t)s0 * 32 + 4 * p);
            uint4 g1 = *(const uint4*)(Tsb + (size_t)s1 * 32 + 4 * p);
            acc[0] += bf_lo(g0.x); acc[1] += bf_hi(g0.x);
            acc[2] += bf_lo(g0.y); acc[3] += bf_hi(g0.y);
            acc[4] += bf_lo(g0.z); acc[5] += bf_hi(g0.z);
            acc[6] += bf_lo(g0.w); acc[7] += bf_hi(g0.w);
            acc[0] += bf_lo(g1.x); acc[1] += bf_hi(g1.x);
            acc[2] += bf_lo(g1.y); acc[3] += bf_hi(g1.y);
            acc[4] += bf_lo(g1.z); acc[5] += bf_hi(g1.z);
            acc[6] += bf_lo(g1.w); acc[7] += bf_hi(g1.w);
        }
        for (; j < bn; j += 8) {          // tail: 8 edges per step, predicated
            int idx = j + o;
            int s = __shfl(cv, idx & 63, 64);  // OOB lanes -> some valid addr
            uint4 g = *(const uint4*)(Tsb + (size_t)s * 32 + 4 * p);
            if (idx < bn) {
                acc[0] += bf_lo(g.x); acc[1] += bf_hi(g.x);
                acc[2] += bf_lo(g.y); acc[3] += bf_hi(g.y);
                acc[4] += bf_lo(g.z); acc[5] += bf_hi(g.z);
                acc[6] += bf_lo(g.w); acc[7] += bf_hi(g.w);
            }
        }
    }
    // combine octants
#pragma unroll
    for (int k = 0; k < 8; ++k) {
        acc[k] += __shfl_xor(acc[k], 8, 64);
        acc[k] += __shfl_xor(acc[k], 16, 64);
        acc[k] += __shfl_xor(acc[k], 32, 64);
    }
    float dq = disqrt[node];
    float4 bv0 = *(const float4*)(bias + 8 * p);
    float4 bv1 = *(const float4*)(bias + 8 * p + 4);
    float r[8];
    r[0] = fmaxf(acc[0] * dq + bv0.x, 0.f);
    r[1] = fmaxf(acc[1] * dq + bv0.y, 0.f);
    r[2] = fmaxf(acc[2] * dq + bv0.z, 0.f);
    r[3] = fmaxf(acc[3] * dq + bv0.w, 0.f);
    r[4] = fmaxf(acc[4] * dq + bv1.x, 0.f);
    r[5] = fmaxf(acc[5] * dq + bv1.y, 0.f);
    r[6] = fmaxf(acc[6] * dq + bv1.z, 0.f);
    r[7] = fmaxf(acc[7] * dq + bv1.w, 0.f);
    if (!FUSE_FC) {
        if (o == 0) {   // pack to bf16 for gemm_tile_b
            uint4 pk;
            pk.x = pack_bf16x2(r[0], r[1]);
            pk.y = pack_bf16x2(r[2], r[3]);
            pk.z = pack_bf16x2(r[4], r[5]);
            pk.w = pack_bf16x2(r[6], r[7]);
            *(uint4*)(outb + (size_t)node * 32 + 4 * p) = pk;
        }
    } else {
        float4 wv0 = *(const float4*)(wfc + 8 * p);
        float4 wv1 = *(const float4*)(wfc + 8 * p + 4);
        float v = r[0] * wv0.x + r[1] * wv0.y + r[2] * wv0.z + r[3] * wv0.w +
                  r[4] * wv1.x + r[5] * wv1.y + r[6] * wv1.z + r[7] * wv1.w;
        v += __shfl_down(v, 4, 64);
        v += __shfl_down(v, 2, 64);
        v += __shfl_down(v, 1, 64);
        if (lane == 0) outf[node] = v + bfc[0];
    }
}

extern "C" void kernel_launch(void* const* d_in, const int* in_sizes, int n_in,
                              void* d_out, int out_size, void* d_ws, size_t ws_size,
                              hipStream_t stream) {
    const float* x   = (const float*)d_in[0];
    const int*   ei  = (const int*)d_in[1];
    const float* W1  = (const float*)d_in[2];
    const float* b1  = (const float*)d_in[3];
    const float* W2  = (const float*)d_in[4];
    const float* b2  = (const float*)d_in[5];
    const float* Wfc = (const float*)d_in[6];
    const float* bfc = (const float*)d_in[7];
    float* out = (float*)d_out;

    const int N = in_sizes[0] / IN_DIM;
    const int E = in_sizes[1] / 2;
    const int* src = ei;
    const int* dst = ei + E;
    const int NC    = (N + 1023) >> 10;      // coarse buckets (1024 nodes each)
    const int chunk = (E + B1 - 1) / B1;     // edges per level-1 block

    // ---- workspace carve-up (256B aligned) ----
    char* w = (char*)d_ws;
    auto alloc = [&](size_t bytes) {
        void* p = (void*)w;
        w += (bytes + 255) & ~(size_t)255;
        return p;
    };
    int*   row_off = (int*)alloc((size_t)(N + 1) * 4);
    float* disqrt  = (float*)alloc((size_t)N * 4);
    int*   goff    = (int*)alloc((size_t)NC * B1 * 4);
    int*   col     = (int*)alloc((size_t)E * 4);
    // scratch region reused: packed pairs (E*4) first, then Ts bf16 (N*128B)
    size_t scrA = (size_t)E * 4, scrB = (size_t)N * HID * 2;
    void*  scr  = alloc(scrA > scrB ? scrA : scrB);
    uint*  h1b  = (uint*)alloc((size_t)N * HID * 2);   // h1 in packed bf16
    uint*  pairs = (uint*)scr;
    uint*  Tsb   = (uint*)scr;

    // ---- build CSR (exact two-level counting sort, packed pairs) ----
    hist1<<<B1, 512, 0, stream>>>(dst, goff, E, NC, chunk);
    scan_mat<<<1, 1024, 0, stream>>>(goff, NC * B1, row_off, N);
    scatter1<<<B1, 512, 0, stream>>>(src, dst, goff, pairs, E, NC, chunk);
    build_csr<<<NC, 1024, 0, stream>>>(pairs, goff, row_off, disqrt, col, E, NC, N);

    // ---- layer 1 ----
    gemm_tile<IN_DIM><<<(N + 63) / 64, 256, 0, stream>>>(x, W1, disqrt, Tsb, N);
    agg_kernel<false><<<(N + 3) / 4, 256, 0, stream>>>(Tsb, row_off, col, disqrt,
                                                       b1, nullptr, nullptr,
                                                       h1b, nullptr, N);

    // ---- layer 2 + fused fc ----
    gemm_tile_b<<<(N + 63) / 64, 256, 0, stream>>>(h1b, W2, disqrt, Tsb, N);
    agg_kernel<true><<<(N + 3) / 4, 256, 0, stream>>>(Tsb, row_off, col, disqrt,
                                                      b2, Wfc, bfc,
                                                      nullptr, out, N);
}